// Round 12
// baseline (233.230 us; speedup 1.0000x reference)
//
#include <hip/hip_runtime.h>
#include <math.h>

typedef __bf16 bf16x8 __attribute__((ext_vector_type(8)));
typedef float f32x4 __attribute__((ext_vector_type(4)));
typedef _Float16 f16;
typedef _Float16 f16x8 __attribute__((ext_vector_type(8)));

#define B_ 4
#define S_ 1024
#define D_ 768
#define F_ 3072
#define E_ 8
#define NTOK 4096
#define NSLOTP 9216   // 8192 slots + per-expert pad to 128

__device__ __forceinline__ void gload_lds16(const void* g, void* s) {
  __builtin_amdgcn_global_load_lds((const __attribute__((address_space(1))) void*)g,
                                   (__attribute__((address_space(3))) void*)s, 16, 0, 0);
}

__device__ __forceinline__ float gelu_f(float v) {
  float u = v * (0.7978845608f + 0.0356774081f * v * v);
  float t = 1.f - 2.f / (1.f + __expf(2.f * u));   // tanh(u), correct +/-inf limits
  return 0.5f * v * (1.f + t);
}

// ---------------- router: fp32 logits, softmax, top-2, renorm (NO atomics) ----------------
__global__ __launch_bounds__(256) void k_router(const float* __restrict__ x,
    const float* __restrict__ wr, int* __restrict__ tki, float* __restrict__ tkw) {
  int wid = threadIdx.x >> 6, lane = threadIdx.x & 63;
  int t = blockIdx.x * 4 + wid;
  const float* xp = x + (size_t)t * D_;
  float pa[E_];
#pragma unroll
  for (int e = 0; e < E_; ++e) pa[e] = 0.f;
#pragma unroll
  for (int it = 0; it < D_ / 64; ++it) {
    int d = it * 64 + lane;
    float xv = xp[d];
    const float4* wp = (const float4*)(wr + (size_t)d * E_);
    float4 a = wp[0], b = wp[1];
    pa[0] += xv * a.x; pa[1] += xv * a.y; pa[2] += xv * a.z; pa[3] += xv * a.w;
    pa[4] += xv * b.x; pa[5] += xv * b.y; pa[6] += xv * b.z; pa[7] += xv * b.w;
  }
#pragma unroll
  for (int e = 0; e < E_; ++e) {
    float v = pa[e];
    for (int off = 32; off; off >>= 1) v += __shfl_xor(v, off);
    pa[e] = v;
  }
  if (lane == 0) {
    float m = pa[0];
#pragma unroll
    for (int e = 1; e < E_; ++e) m = fmaxf(m, pa[e]);
    float p[E_], s = 0.f;
#pragma unroll
    for (int e = 0; e < E_; ++e) { p[e] = expf(pa[e] - m); s += p[e]; }
#pragma unroll
    for (int e = 0; e < E_; ++e) p[e] = p[e] / s;
    int i0 = 0; float b0 = p[0];
#pragma unroll
    for (int e = 1; e < E_; ++e) if (p[e] > b0) { b0 = p[e]; i0 = e; }
    int i1 = -1; float b1v = -1.f;
#pragma unroll
    for (int e = 0; e < E_; ++e) if (e != i0 && p[e] > b1v) { b1v = p[e]; i1 = e; }
    float den = b0 + b1v + 1e-8f;
    tki[t * 2] = i0; tki[t * 2 + 1] = i1;
    tkw[t * 2] = b0 / den; tkw[t * 2 + 1] = b1v / den;
  }
}

// ---- single-block routing: histogram -> scan -> 128-aligned offsets -> ordered slots ----
__global__ __launch_bounds__(256) void k_route_all(const int* __restrict__ tki,
    int* __restrict__ stok, int* __restrict__ tslot, int* __restrict__ aoff) {
  __shared__ int cl[256][E_ + 1];   // +1 pad: spread histogram banks
  __shared__ int tot[E_];
  __shared__ int aoffA[E_ + 1];
  int tid = threadIdx.x;
  for (int i = tid; i < NSLOTP; i += 256) stok[i] = -1;
#pragma unroll
  for (int e = 0; e < E_; ++e) cl[tid][e] = 0;
  int t0 = tid * (NTOK / 256);
#pragma unroll
  for (int i = 0; i < NTOK / 256; ++i) {
    cl[tid][tki[(t0 + i) * 2]]++;
    cl[tid][tki[(t0 + i) * 2 + 1]]++;
  }
  __syncthreads();
  if (tid < E_) {
    int run = 0;
    for (int i = 0; i < 256; ++i) { int v = cl[i][tid]; cl[i][tid] = run; run += v; }
    tot[tid] = run;
  }
  __syncthreads();
  if (tid == 0) {
    int a = 0; aoffA[0] = 0; aoff[0] = 0;
    for (int e = 0; e < E_; ++e) { a += ((tot[e] + 127) >> 7) << 7; aoffA[e + 1] = a; aoff[e + 1] = a; }
  }
  __syncthreads();
#pragma unroll
  for (int i = 0; i < NTOK / 256; ++i) {
    int t = t0 + i;
#pragma unroll
    for (int k = 0; k < 2; ++k) {
      int e = tki[t * 2 + k];
      int pos = aoffA[e] + cl[tid][e];
      cl[tid][e]++;
      stok[pos] = t;
      tslot[t * 2 + k] = pos;
    }
  }
}

// -------- gather x rows into bf16 slot matrix (zeros for padding) --------
__global__ __launch_bounds__(256) void k_gather(const float* __restrict__ x,
    const int* __restrict__ stok, __bf16* __restrict__ Xg) {
  int i8 = blockIdx.x * 256 + threadIdx.x;
  int flat = i8 * 8;
  int row = flat / D_;
  int col = flat - row * D_;
  int tok = stok[row];
  bf16x8 v;
  if (tok >= 0) {
    const float4* s = (const float4*)(x + (size_t)tok * D_ + col);
    float4 a = s[0], b = s[1];
    v[0] = (__bf16)a.x; v[1] = (__bf16)a.y; v[2] = (__bf16)a.z; v[3] = (__bf16)a.w;
    v[4] = (__bf16)b.x; v[5] = (__bf16)b.y; v[6] = (__bf16)b.z; v[7] = (__bf16)b.w;
  } else {
#pragma unroll
    for (int k = 0; k < 8; ++k) v[k] = (__bf16)0.f;
  }
  *(bf16x8*)(Xg + (size_t)flat) = v;
}

// -------- fp32 [R][C] -> bf16 [C][R] per expert; 128-row tile, 256B write segments --------
__global__ __launch_bounds__(256) void k_transpose(const float* __restrict__ in,
    __bf16* __restrict__ outp, int R, int C) {
  __shared__ float Ts[128][65];
  int e = blockIdx.z;
  int r0 = blockIdx.y * 128, c0 = blockIdx.x * 64;
  const float* ip = in + (size_t)e * R * C + (size_t)r0 * C + c0;
  int lr = threadIdx.x >> 4;          // 0..15
  int lc = (threadIdx.x & 15) * 4;    // 0..60
#pragma unroll
  for (int it = 0; it < 8; ++it) {
    int r = lr + it * 16;
    float4 v = *(const float4*)(ip + (size_t)r * C + lc);
    Ts[r][lc] = v.x; Ts[r][lc + 1] = v.y; Ts[r][lc + 2] = v.z; Ts[r][lc + 3] = v.w;
  }
  __syncthreads();
  int cc = threadIdx.x >> 4;          // 0..15 (column within pass)
  int rr = (threadIdx.x & 15) * 8;    // 0..120 (16 threads x 16B = 256B per column)
  __bf16* op = outp + (size_t)e * R * C + (size_t)c0 * R + r0 + rr;
#pragma unroll
  for (int it = 0; it < 4; ++it) {
    int c = cc + it * 16;
    bf16x8 v;
#pragma unroll
    for (int i = 0; i < 8; ++i) v[i] = (__bf16)Ts[rr + i][c];
    *(bf16x8*)(op + (size_t)c * R) = v;
  }
}

// ===== GEMM1: proven 2-phase dbuf, BM=128, BN=192, BK=32, 8 waves (2x4, 64x48/wave) =====
// LDS 40KB -> 4 blocks/CU = 32 waves/CU (wave cap).  H = gelu(Xg @ w1t^T + b1)
__global__ __launch_bounds__(512, 4) void k_gemm1(
    const __bf16* __restrict__ A, const __bf16* __restrict__ Bt,
    const float* __restrict__ bias, const int* __restrict__ aoff,
    __bf16* __restrict__ Hout) {
  constexpr int KST = D_, N = F_;
  constexpr int BN = 192;
  constexpr int ASZ = 128 * 32;
  constexpr int BSZ = BN * 32;                     // 6144 elems
  constexpr int NK = KST / 32;
  constexpr int NB = N / BN;                       // 16
  constexpr int NMB = NSLOTP / 128;                // 72
  constexpr int NWG = NB * NMB;                    // 1152

  __shared__ __align__(16) __bf16 Als[2 * ASZ];    // 16KB
  __shared__ __align__(16) __bf16 Bls[2 * BSZ];    // 24KB

  int bswz = (blockIdx.x & 7) * (NWG / 8) + (blockIdx.x >> 3);   // bijective, NWG%8==0
  int mb = bswz % NMB, nb = bswz / NMB;                          // mb-fast: B panel L2-hot
  int row0 = mb * 128;
  if (row0 >= aoff[E_]) return;
  int e = 0;
#pragma unroll
  for (int q = 0; q < E_; ++q) if (row0 >= aoff[q + 1]) e = q + 1;
  const __bf16* Bp = Bt + (size_t)e * D_ * F_;

  int tid = threadIdx.x, w = tid >> 6, l = tid & 63;
  int lr = l >> 2, ls = l & 3;      // staging lane -> row-in-16 / 16B slot
  int fr = l & 15, fg = l >> 4;     // fragment lane -> row / k-group
  int wrow = (w >> 2) * 64, wcol = (w & 3) * 48;

  auto STAGE = [&](int kt, int b) {
    int k0 = kt * 32;
    {
      int rowA = w * 16 + lr;                      // A: 8 units, 1/wave
      int sA = ls ^ ((rowA >> 1) & 3);
      gload_lds16(A + (size_t)(row0 + rowA) * KST + k0 + sA * 8, Als + b * ASZ + w * 512);
    }
    {
      int rowB = w * 16 + lr;                      // B units 0..7: 1/wave
      int sB = ls ^ ((rowB >> 1) & 3);
      gload_lds16(Bp + (size_t)(nb * BN + rowB) * KST + k0 + sB * 8, Bls + b * BSZ + w * 512);
    }
    if (w < 4) {                                   // B units 8..11: waves 0-3
      int u = 8 + w;
      int rowB = u * 16 + lr;
      int sB = ls ^ ((rowB >> 1) & 3);
      gload_lds16(Bp + (size_t)(nb * BN + rowB) * KST + k0 + sB * 8, Bls + b * BSZ + u * 512);
    }
  };

  f32x4 acc[4][3] = {};
  STAGE(0, 0);
  asm volatile("s_waitcnt vmcnt(0)" ::: "memory");
  __builtin_amdgcn_sched_barrier(0);
  __builtin_amdgcn_s_barrier();
  for (int t = 0; t < NK; ++t) {
    int cur = t & 1;
    if (t + 1 < NK) STAGE(t + 1, cur ^ 1);         // issue next-tile loads FIRST
    __builtin_amdgcn_sched_barrier(0);
    bf16x8 af[4], bfr[3];
#pragma unroll
    for (int i = 0; i < 4; ++i) {
      int rl = wrow + i * 16 + fr;
      af[i] = *(const bf16x8*)(Als + cur * ASZ + rl * 32 + ((fg ^ ((rl >> 1) & 3)) << 3));
    }
#pragma unroll
    for (int j = 0; j < 3; ++j) {
      int nl = wcol + j * 16 + fr;
      bfr[j] = *(const bf16x8*)(Bls + cur * BSZ + nl * 32 + ((fg ^ ((nl >> 1) & 3)) << 3));
    }
#pragma unroll
    for (int i = 0; i < 4; ++i)
#pragma unroll
      for (int j = 0; j < 3; ++j)
        acc[i][j] = __builtin_amdgcn_mfma_f32_16x16x32_bf16(af[i], bfr[j], acc[i][j], 0, 0, 0);
    __builtin_amdgcn_sched_barrier(0);
    asm volatile("s_waitcnt vmcnt(0)" ::: "memory");  // hidden under MFMA
    __builtin_amdgcn_s_barrier();
  }

#pragma unroll
  for (int j = 0; j < 3; ++j) {
    int col = nb * BN + wcol + j * 16 + fr;
    float bv = bias[e * N + col];
#pragma unroll
    for (int i = 0; i < 4; ++i) {
#pragma unroll
      for (int r = 0; r < 4; ++r) {
        int row = row0 + wrow + i * 16 + fg * 4 + r;
        Hout[(size_t)row * N + col] = (__bf16)gelu_f(acc[i][j][r] + bv);
      }
    }
  }
}

// ===== GEMM2: 2-phase dbuf, BM=128, BN=192, BK=32, split-K=2, fp16 partials =====
// E[kh] = H[:,khalf] @ w2t[:,khalf]^T (+b2 if kh==0)
__global__ __launch_bounds__(512, 4) void k_gemm2(
    const __bf16* __restrict__ A, const __bf16* __restrict__ Bt,
    const float* __restrict__ bias, const int* __restrict__ aoff,
    f16* __restrict__ E0, f16* __restrict__ E1) {
  constexpr int KST = F_, N = D_;
  constexpr int BN = 192;
  constexpr int ASZ = 128 * 32;
  constexpr int BSZ = BN * 32;
  constexpr int NK = KST / 32 / 2;                 // 48
  constexpr int NB = N / BN;                       // 4
  constexpr int NMB = NSLOTP / 128;                // 72
  constexpr int NWGB = NB * NMB;                   // 288
  constexpr int NWG = NWGB * 2;                    // 576

  __shared__ __align__(16) __bf16 Als[2 * ASZ];
  __shared__ __align__(16) __bf16 Bls[2 * BSZ];

  int bswz = (blockIdx.x & 7) * (NWG / 8) + (blockIdx.x >> 3);
  int kh = bswz / NWGB;
  int rem = bswz % NWGB;
  int mb = rem % NMB, nb = rem / NMB;
  int row0 = mb * 128;
  if (row0 >= aoff[E_]) return;
  int e = 0;
#pragma unroll
  for (int q = 0; q < E_; ++q) if (row0 >= aoff[q + 1]) e = q + 1;
  const __bf16* Bp = Bt + (size_t)e * D_ * F_;
  int kbase = kh * (KST / 2);

  int tid = threadIdx.x, w = tid >> 6, l = tid & 63;
  int lr = l >> 2, ls = l & 3;
  int fr = l & 15, fg = l >> 4;
  int wrow = (w >> 2) * 64, wcol = (w & 3) * 48;

  auto STAGE = [&](int kt, int b) {
    int k0 = kbase + kt * 32;
    {
      int rowA = w * 16 + lr;
      int sA = ls ^ ((rowA >> 1) & 3);
      gload_lds16(A + (size_t)(row0 + rowA) * KST + k0 + sA * 8, Als + b * ASZ + w * 512);
    }
    {
      int rowB = w * 16 + lr;
      int sB = ls ^ ((rowB >> 1) & 3);
      gload_lds16(Bp + (size_t)(nb * BN + rowB) * KST + k0 + sB * 8, Bls + b * BSZ + w * 512);
    }
    if (w < 4) {
      int u = 8 + w;
      int rowB = u * 16 + lr;
      int sB = ls ^ ((rowB >> 1) & 3);
      gload_lds16(Bp + (size_t)(nb * BN + rowB) * KST + k0 + sB * 8, Bls + b * BSZ + u * 512);
    }
  };

  f32x4 acc[4][3] = {};
  STAGE(0, 0);
  asm volatile("s_waitcnt vmcnt(0)" ::: "memory");
  __builtin_amdgcn_sched_barrier(0);
  __builtin_amdgcn_s_barrier();
  for (int t = 0; t < NK; ++t) {
    int cur = t & 1;
    if (t + 1 < NK) STAGE(t + 1, cur ^ 1);
    __builtin_amdgcn_sched_barrier(0);
    bf16x8 af[4], bfr[3];
#pragma unroll
    for (int i = 0; i < 4; ++i) {
      int rl = wrow + i * 16 + fr;
      af[i] = *(const bf16x8*)(Als + cur * ASZ + rl * 32 + ((fg ^ ((rl >> 1) & 3)) << 3));
    }
#pragma unroll
    for (int j = 0; j < 3; ++j) {
      int nl = wcol + j * 16 + fr;
      bfr[j] = *(const bf16x8*)(Bls + cur * BSZ + nl * 32 + ((fg ^ ((nl >> 1) & 3)) << 3));
    }
#pragma unroll
    for (int i = 0; i < 4; ++i)
#pragma unroll
      for (int j = 0; j < 3; ++j)
        acc[i][j] = __builtin_amdgcn_mfma_f32_16x16x32_bf16(af[i], bfr[j], acc[i][j], 0, 0, 0);
    __builtin_amdgcn_sched_barrier(0);
    asm volatile("s_waitcnt vmcnt(0)" ::: "memory");
    __builtin_amdgcn_s_barrier();
  }

  f16* Ep = (kh == 0) ? E0 : E1;
#pragma unroll
  for (int j = 0; j < 3; ++j) {
    int col = nb * BN + wcol + j * 16 + fr;
    float bv = (kh == 0) ? bias[e * N + col] : 0.f;
#pragma unroll
    for (int i = 0; i < 4; ++i) {
#pragma unroll
      for (int r = 0; r < 4; ++r) {
        int row = row0 + wrow + i * 16 + fg * 4 + r;
        Ep[(size_t)row * N + col] = (f16)(acc[i][j][r] + bv);
      }
    }
  }
}

// -------- combine: out[t] = w0*(E0+E1)[s0] + w1*(E0+E1)[s1]  (fp16 partials) --------
__global__ __launch_bounds__(256) void k_combine(const f16* __restrict__ E0,
    const f16* __restrict__ E1, const int* __restrict__ tslot,
    const float* __restrict__ tkw, float* __restrict__ out) {
  int idx = blockIdx.x * 256 + threadIdx.x;        // per 8 elems
  int t = idx / (D_ / 8);
  int c8 = (idx - t * (D_ / 8)) * 8;
  int s0 = tslot[2 * t], s1 = tslot[2 * t + 1];
  float w0 = tkw[2 * t], w1 = tkw[2 * t + 1];
  f16x8 a0 = *(const f16x8*)(E0 + (size_t)s0 * D_ + c8);
  f16x8 b0 = *(const f16x8*)(E0 + (size_t)s1 * D_ + c8);
  f16x8 a1 = *(const f16x8*)(E1 + (size_t)s0 * D_ + c8);
  f16x8 b1 = *(const f16x8*)(E1 + (size_t)s1 * D_ + c8);
  float o[8];
#pragma unroll
  for (int k = 0; k < 8; ++k)
    o[k] = w0 * ((float)a0[k] + (float)a1[k]) + w1 * ((float)b0[k] + (float)b1[k]);
  *(float4*)(out + (size_t)t * D_ + c8)     = *(float4*)&o[0];
  *(float4*)(out + (size_t)t * D_ + c8 + 4) = *(float4*)&o[4];
}

extern "C" void kernel_launch(void* const* d_in, const int* in_sizes, int n_in,
                              void* d_out, int out_size, void* d_ws, size_t ws_size,
                              hipStream_t stream) {
  const float* x  = (const float*)d_in[0];
  const float* wr = (const float*)d_in[1];
  const float* w1 = (const float*)d_in[2];
  const float* b1 = (const float*)d_in[3];
  const float* w2 = (const float*)d_in[4];
  const float* b2 = (const float*)d_in[5];
  float* out = (float*)d_out;

  char* ws = (char*)d_ws;
  size_t o = 0;
  __bf16* wt  = (__bf16*)(ws + o); o += (size_t)E_ * D_ * F_ * 2;  // w1t, then w2t after GEMM1
  __bf16* Xg  = (__bf16*)(ws + o); o += (size_t)NSLOTP * D_ * 2;   // dead after GEMM1
  __bf16* H   = (__bf16*)(ws + o); o += (size_t)NSLOTP * F_ * 2;
  f16*   E1p  = (f16*)(ws + o);   o += (size_t)NSLOTP * D_ * 2;
  int*   tki  = (int*)(ws + o);   o += (size_t)NTOK * 2 * 4;
  float* tkw  = (float*)(ws + o); o += (size_t)NTOK * 2 * 4;
  int*   stok = (int*)(ws + o);   o += (size_t)NSLOTP * 4;
  int*   tslot= (int*)(ws + o);   o += (size_t)NTOK * 2 * 4;
  int*   aoff = (int*)(ws + o);   o += 64;
  f16*   E0p  = (f16*)Xg;         // alias: Xg dead after GEMM1, identical size
  if (ws_size < o) return;        // ~123 MB (< proven 147 MB)

  k_router<<<NTOK / 4, 256, 0, stream>>>(x, wr, tki, tkw);
  k_route_all<<<1, 256, 0, stream>>>(tki, stok, tslot, aoff);
  k_gather<<<(NSLOTP * D_ / 8) / 256, 256, 0, stream>>>(x, stok, Xg);
  // w1 transpose: R=768, C=3072 -> grid (48, 6, 8)
  k_transpose<<<dim3(F_ / 64, D_ / 128, E_), 256, 0, stream>>>(w1, wt, D_, F_);
  // GEMM1: BN=192 -> 16*72 = 1152 blocks, 4 blocks/CU
  k_gemm1<<<(F_ / 192) * (NSLOTP / 128), 512, 0, stream>>>(Xg, wt, b1, aoff, H);
  // w2 transpose into the (now dead) wt slot: R=3072, C=768 -> grid (12, 24, 8)
  k_transpose<<<dim3(D_ / 64, F_ / 128, E_), 256, 0, stream>>>(w2, wt, F_, D_);
  // GEMM2: BN=192, split-K=2 -> 2*4*72 = 576 blocks, fp16 partials
  k_gemm2<<<2 * (D_ / 192) * (NSLOTP / 128), 512, 0, stream>>>(
      H, wt, b2, aoff, E0p, E1p);
  k_combine<<<NTOK * (D_ / 8) / 256, 256, 0, stream>>>(E0p, E1p, tslot, tkw, out);
}

// Round 13
// 217.503 us; speedup vs baseline: 1.0723x; 1.0723x over previous
//
#include <hip/hip_runtime.h>
#include <math.h>

typedef __bf16 bf16x8 __attribute__((ext_vector_type(8)));
typedef float f32x4 __attribute__((ext_vector_type(4)));
typedef _Float16 f16;
typedef _Float16 f16x8 __attribute__((ext_vector_type(8)));

#define B_ 4
#define S_ 1024
#define D_ 768
#define F_ 3072
#define E_ 8
#define NTOK 4096
#define NSLOTP 9216   // 8192 slots + per-expert pad to 128

__device__ __forceinline__ void gload_lds16(const void* g, void* s) {
  __builtin_amdgcn_global_load_lds((const __attribute__((address_space(1))) void*)g,
                                   (__attribute__((address_space(3))) void*)s, 16, 0, 0);
}

__device__ __forceinline__ float gelu_f(float v) {
  float u = v * (0.7978845608f + 0.0356774081f * v * v);
  float t = 1.f - 2.f / (1.f + __expf(2.f * u));   // tanh(u), correct +/-inf limits
  return 0.5f * v * (1.f + t);
}

// ---------------- router: fp32 logits, softmax, top-2, renorm (NO atomics) ----------------
__global__ __launch_bounds__(256) void k_router(const float* __restrict__ x,
    const float* __restrict__ wr, int* __restrict__ tki, float* __restrict__ tkw) {
  int wid = threadIdx.x >> 6, lane = threadIdx.x & 63;
  int t = blockIdx.x * 4 + wid;
  const float* xp = x + (size_t)t * D_;
  float pa[E_];
#pragma unroll
  for (int e = 0; e < E_; ++e) pa[e] = 0.f;
#pragma unroll
  for (int it = 0; it < D_ / 64; ++it) {
    int d = it * 64 + lane;
    float xv = xp[d];
    const float4* wp = (const float4*)(wr + (size_t)d * E_);
    float4 a = wp[0], b = wp[1];
    pa[0] += xv * a.x; pa[1] += xv * a.y; pa[2] += xv * a.z; pa[3] += xv * a.w;
    pa[4] += xv * b.x; pa[5] += xv * b.y; pa[6] += xv * b.z; pa[7] += xv * b.w;
  }
#pragma unroll
  for (int e = 0; e < E_; ++e) {
    float v = pa[e];
    for (int off = 32; off; off >>= 1) v += __shfl_xor(v, off);
    pa[e] = v;
  }
  if (lane == 0) {
    float m = pa[0];
#pragma unroll
    for (int e = 1; e < E_; ++e) m = fmaxf(m, pa[e]);
    float p[E_], s = 0.f;
#pragma unroll
    for (int e = 0; e < E_; ++e) { p[e] = expf(pa[e] - m); s += p[e]; }
#pragma unroll
    for (int e = 0; e < E_; ++e) p[e] = p[e] / s;
    int i0 = 0; float b0 = p[0];
#pragma unroll
    for (int e = 1; e < E_; ++e) if (p[e] > b0) { b0 = p[e]; i0 = e; }
    int i1 = -1; float b1v = -1.f;
#pragma unroll
    for (int e = 0; e < E_; ++e) if (e != i0 && p[e] > b1v) { b1v = p[e]; i1 = e; }
    float den = b0 + b1v + 1e-8f;
    tki[t * 2] = i0; tki[t * 2 + 1] = i1;
    tkw[t * 2] = b0 / den; tkw[t * 2 + 1] = b1v / den;
  }
}

// ---- single-block routing: histogram -> scan -> 128-aligned offsets -> ordered slots ----
__global__ __launch_bounds__(256) void k_route_all(const int* __restrict__ tki,
    int* __restrict__ stok, int* __restrict__ tslot, int* __restrict__ aoff) {
  __shared__ int cl[256][E_ + 1];   // +1 pad: spread histogram banks
  __shared__ int tot[E_];
  __shared__ int aoffA[E_ + 1];
  int tid = threadIdx.x;
  for (int i = tid; i < NSLOTP; i += 256) stok[i] = -1;
#pragma unroll
  for (int e = 0; e < E_; ++e) cl[tid][e] = 0;
  int t0 = tid * (NTOK / 256);
#pragma unroll
  for (int i = 0; i < NTOK / 256; ++i) {
    cl[tid][tki[(t0 + i) * 2]]++;
    cl[tid][tki[(t0 + i) * 2 + 1]]++;
  }
  __syncthreads();
  if (tid < E_) {
    int run = 0;
    for (int i = 0; i < 256; ++i) { int v = cl[i][tid]; cl[i][tid] = run; run += v; }
    tot[tid] = run;
  }
  __syncthreads();
  if (tid == 0) {
    int a = 0; aoffA[0] = 0; aoff[0] = 0;
    for (int e = 0; e < E_; ++e) { a += ((tot[e] + 127) >> 7) << 7; aoffA[e + 1] = a; aoff[e + 1] = a; }
  }
  __syncthreads();
#pragma unroll
  for (int i = 0; i < NTOK / 256; ++i) {
    int t = t0 + i;
#pragma unroll
    for (int k = 0; k < 2; ++k) {
      int e = tki[t * 2 + k];
      int pos = aoffA[e] + cl[tid][e];
      cl[tid][e]++;
      stok[pos] = t;
      tslot[t * 2 + k] = pos;
    }
  }
}

// -------- gather x rows into bf16 slot matrix (zeros for padding) --------
__global__ __launch_bounds__(256) void k_gather(const float* __restrict__ x,
    const int* __restrict__ stok, __bf16* __restrict__ Xg) {
  int i8 = blockIdx.x * 256 + threadIdx.x;
  int flat = i8 * 8;
  int row = flat / D_;
  int col = flat - row * D_;
  int tok = stok[row];
  bf16x8 v;
  if (tok >= 0) {
    const float4* s = (const float4*)(x + (size_t)tok * D_ + col);
    float4 a = s[0], b = s[1];
    v[0] = (__bf16)a.x; v[1] = (__bf16)a.y; v[2] = (__bf16)a.z; v[3] = (__bf16)a.w;
    v[4] = (__bf16)b.x; v[5] = (__bf16)b.y; v[6] = (__bf16)b.z; v[7] = (__bf16)b.w;
  } else {
#pragma unroll
    for (int k = 0; k < 8; ++k) v[k] = (__bf16)0.f;
  }
  *(bf16x8*)(Xg + (size_t)flat) = v;
}

// -------- fp32 [R][C] -> bf16 [C][R] per expert; 128-row tile, 256B write segments --------
__global__ __launch_bounds__(256) void k_transpose(const float* __restrict__ in,
    __bf16* __restrict__ outp, int R, int C) {
  __shared__ float Ts[128][65];
  int e = blockIdx.z;
  int r0 = blockIdx.y * 128, c0 = blockIdx.x * 64;
  const float* ip = in + (size_t)e * R * C + (size_t)r0 * C + c0;
  int lr = threadIdx.x >> 4;          // 0..15
  int lc = (threadIdx.x & 15) * 4;    // 0..60
#pragma unroll
  for (int it = 0; it < 8; ++it) {
    int r = lr + it * 16;
    float4 v = *(const float4*)(ip + (size_t)r * C + lc);
    Ts[r][lc] = v.x; Ts[r][lc + 1] = v.y; Ts[r][lc + 2] = v.z; Ts[r][lc + 3] = v.w;
  }
  __syncthreads();
  int cc = threadIdx.x >> 4;          // 0..15 (column within pass)
  int rr = (threadIdx.x & 15) * 8;    // 0..120 (16 threads x 16B = 256B per column)
  __bf16* op = outp + (size_t)e * R * C + (size_t)c0 * R + r0 + rr;
#pragma unroll
  for (int it = 0; it < 4; ++it) {
    int c = cc + it * 16;
    bf16x8 v;
#pragma unroll
    for (int i = 0; i < 8; ++i) v[i] = (__bf16)Ts[rr + i][c];
    *(bf16x8*)(op + (size_t)c * R) = v;
  }
}

// ===== GEMM1 (proven 79.6us): 2-phase dbuf, BM=128, BN=256, BK=32, =====
// ===== 8 waves (2x4, per-wave 64x64), 48KB LDS.                     =====
// H = gelu(Xg @ w1t^T + b1)
__global__ __launch_bounds__(512, 4) void k_gemm1(
    const __bf16* __restrict__ A, const __bf16* __restrict__ Bt,
    const float* __restrict__ bias, const int* __restrict__ aoff,
    __bf16* __restrict__ Hout) {
  constexpr int KST = D_, N = F_;
  constexpr int BN = 256;
  constexpr int ASZ = 128 * 32;
  constexpr int BSZ = BN * 32;
  constexpr int NK = KST / 32;
  constexpr int NB = N / BN;
  constexpr int NMB = NSLOTP / 128;
  constexpr int NWG = NB * NMB;                    // 12*72 = 864

  __shared__ __align__(16) __bf16 Als[2 * ASZ];
  __shared__ __align__(16) __bf16 Bls[2 * BSZ];

  int bswz = (blockIdx.x & 7) * (NWG / 8) + (blockIdx.x >> 3);   // bijective, NWG%8==0
  int mb = bswz % NMB, nb = bswz / NMB;                          // mb-fast: B panel L2-hot
  int row0 = mb * 128;
  if (row0 >= aoff[E_]) return;
  int e = 0;
#pragma unroll
  for (int q = 0; q < E_; ++q) if (row0 >= aoff[q + 1]) e = q + 1;
  const __bf16* Bp = Bt + (size_t)e * D_ * F_;

  int tid = threadIdx.x, w = tid >> 6, l = tid & 63;
  int lr = l >> 2, ls = l & 3;      // staging lane -> row-in-16 / 16B slot
  int fr = l & 15, fg = l >> 4;     // fragment lane -> row / k-group
  int wrow = (w >> 2) * 64, wcol = (w & 3) * 64;

  auto STAGE = [&](int kt, int b) {
    int k0 = kt * 32;
    {
      int rowA = w * 16 + lr;
      int sA = ls ^ ((rowA >> 1) & 3);
      gload_lds16(A + (size_t)(row0 + rowA) * KST + k0 + sA * 8, Als + b * ASZ + w * 512);
    }
#pragma unroll
    for (int q = 0; q < 2; ++q) {
      int idx = w * 2 + q;
      int rowB = idx * 16 + lr;
      int sB = ls ^ ((rowB >> 1) & 3);
      gload_lds16(Bp + (size_t)(nb * BN + rowB) * KST + k0 + sB * 8, Bls + b * BSZ + idx * 512);
    }
  };

  f32x4 acc[4][4] = {};
  STAGE(0, 0);
  asm volatile("s_waitcnt vmcnt(0)" ::: "memory");
  __builtin_amdgcn_sched_barrier(0);
  __builtin_amdgcn_s_barrier();
  for (int t = 0; t < NK; ++t) {
    int cur = t & 1;
    if (t + 1 < NK) STAGE(t + 1, cur ^ 1);         // issue next-tile loads FIRST
    __builtin_amdgcn_sched_barrier(0);
    bf16x8 af[4], bfr[4];
#pragma unroll
    for (int i = 0; i < 4; ++i) {
      int rl = wrow + i * 16 + fr;
      af[i] = *(const bf16x8*)(Als + cur * ASZ + rl * 32 + ((fg ^ ((rl >> 1) & 3)) << 3));
    }
#pragma unroll
    for (int j = 0; j < 4; ++j) {
      int nl = wcol + j * 16 + fr;
      bfr[j] = *(const bf16x8*)(Bls + cur * BSZ + nl * 32 + ((fg ^ ((nl >> 1) & 3)) << 3));
    }
#pragma unroll
    for (int i = 0; i < 4; ++i)
#pragma unroll
      for (int j = 0; j < 4; ++j)
        acc[i][j] = __builtin_amdgcn_mfma_f32_16x16x32_bf16(af[i], bfr[j], acc[i][j], 0, 0, 0);
    __builtin_amdgcn_sched_barrier(0);
    asm volatile("s_waitcnt vmcnt(0)" ::: "memory");  // hidden under MFMA
    __builtin_amdgcn_s_barrier();
  }

#pragma unroll
  for (int j = 0; j < 4; ++j) {
    int col = nb * BN + wcol + j * 16 + fr;
    float bv = bias[e * N + col];
#pragma unroll
    for (int i = 0; i < 4; ++i) {
#pragma unroll
      for (int r = 0; r < 4; ++r) {
        int row = row0 + wrow + i * 16 + fg * 4 + r;
        Hout[(size_t)row * N + col] = (__bf16)gelu_f(acc[i][j][r] + bv);
      }
    }
  }
}

// ===== GEMM2: 2-phase dbuf, BM=128, BN=256, BK=32, split-K=3, fp16 partials =====
// E[kh] = H[:,kthird] @ w2t[:,kthird]^T (+b2 if kh==0).  648 blocks, all-resident.
__global__ __launch_bounds__(512, 4) void k_gemm2(
    const __bf16* __restrict__ A, const __bf16* __restrict__ Bt,
    const float* __restrict__ bias, const int* __restrict__ aoff,
    f16* __restrict__ E0, f16* __restrict__ E1, f16* __restrict__ E2) {
  constexpr int KST = F_, N = D_;
  constexpr int BN = 256;
  constexpr int ASZ = 128 * 32;
  constexpr int BSZ = BN * 32;
  constexpr int NK = KST / 32 / 3;                 // 32
  constexpr int NB = N / BN;                       // 3
  constexpr int NMB = NSLOTP / 128;                // 72
  constexpr int NWGB = NB * NMB;                   // 216
  constexpr int NWG = NWGB * 3;                    // 648 (%8 == 0)

  __shared__ __align__(16) __bf16 Als[2 * ASZ];
  __shared__ __align__(16) __bf16 Bls[2 * BSZ];

  int bswz = (blockIdx.x & 7) * (NWG / 8) + (blockIdx.x >> 3);
  int kh = bswz / NWGB;
  int rem = bswz % NWGB;
  int mb = rem % NMB, nb = rem / NMB;
  int row0 = mb * 128;
  if (row0 >= aoff[E_]) return;
  int e = 0;
#pragma unroll
  for (int q = 0; q < E_; ++q) if (row0 >= aoff[q + 1]) e = q + 1;
  const __bf16* Bp = Bt + (size_t)e * D_ * F_;
  int kbase = kh * (KST / 3);

  int tid = threadIdx.x, w = tid >> 6, l = tid & 63;
  int lr = l >> 2, ls = l & 3;
  int fr = l & 15, fg = l >> 4;
  int wrow = (w >> 2) * 64, wcol = (w & 3) * 64;

  auto STAGE = [&](int kt, int b) {
    int k0 = kbase + kt * 32;
    {
      int rowA = w * 16 + lr;
      int sA = ls ^ ((rowA >> 1) & 3);
      gload_lds16(A + (size_t)(row0 + rowA) * KST + k0 + sA * 8, Als + b * ASZ + w * 512);
    }
#pragma unroll
    for (int q = 0; q < 2; ++q) {
      int idx = w * 2 + q;
      int rowB = idx * 16 + lr;
      int sB = ls ^ ((rowB >> 1) & 3);
      gload_lds16(Bp + (size_t)(nb * BN + rowB) * KST + k0 + sB * 8, Bls + b * BSZ + idx * 512);
    }
  };

  f32x4 acc[4][4] = {};
  STAGE(0, 0);
  asm volatile("s_waitcnt vmcnt(0)" ::: "memory");
  __builtin_amdgcn_sched_barrier(0);
  __builtin_amdgcn_s_barrier();
  for (int t = 0; t < NK; ++t) {
    int cur = t & 1;
    if (t + 1 < NK) STAGE(t + 1, cur ^ 1);
    __builtin_amdgcn_sched_barrier(0);
    bf16x8 af[4], bfr[4];
#pragma unroll
    for (int i = 0; i < 4; ++i) {
      int rl = wrow + i * 16 + fr;
      af[i] = *(const bf16x8*)(Als + cur * ASZ + rl * 32 + ((fg ^ ((rl >> 1) & 3)) << 3));
    }
#pragma unroll
    for (int j = 0; j < 4; ++j) {
      int nl = wcol + j * 16 + fr;
      bfr[j] = *(const bf16x8*)(Bls + cur * BSZ + nl * 32 + ((fg ^ ((nl >> 1) & 3)) << 3));
    }
#pragma unroll
    for (int i = 0; i < 4; ++i)
#pragma unroll
      for (int j = 0; j < 4; ++j)
        acc[i][j] = __builtin_amdgcn_mfma_f32_16x16x32_bf16(af[i], bfr[j], acc[i][j], 0, 0, 0);
    __builtin_amdgcn_sched_barrier(0);
    asm volatile("s_waitcnt vmcnt(0)" ::: "memory");
    __builtin_amdgcn_s_barrier();
  }

  f16* Ep = (kh == 0) ? E0 : ((kh == 1) ? E1 : E2);
#pragma unroll
  for (int j = 0; j < 4; ++j) {
    int col = nb * BN + wcol + j * 16 + fr;
    float bv = (kh == 0) ? bias[e * N + col] : 0.f;
#pragma unroll
    for (int i = 0; i < 4; ++i) {
#pragma unroll
      for (int r = 0; r < 4; ++r) {
        int row = row0 + wrow + i * 16 + fg * 4 + r;
        Ep[(size_t)row * N + col] = (f16)(acc[i][j][r] + bv);
      }
    }
  }
}

// -------- combine: out[t] = w0*(E0+E1+E2)[s0] + w1*(E0+E1+E2)[s1]  (fp16 partials) --------
__global__ __launch_bounds__(256) void k_combine(const f16* __restrict__ E0,
    const f16* __restrict__ E1, const f16* __restrict__ E2, const int* __restrict__ tslot,
    const float* __restrict__ tkw, float* __restrict__ out) {
  int idx = blockIdx.x * 256 + threadIdx.x;        // per 8 elems
  int t = idx / (D_ / 8);
  int c8 = (idx - t * (D_ / 8)) * 8;
  int s0 = tslot[2 * t], s1 = tslot[2 * t + 1];
  float w0 = tkw[2 * t], w1 = tkw[2 * t + 1];
  f16x8 a0 = *(const f16x8*)(E0 + (size_t)s0 * D_ + c8);
  f16x8 b0 = *(const f16x8*)(E0 + (size_t)s1 * D_ + c8);
  f16x8 a1 = *(const f16x8*)(E1 + (size_t)s0 * D_ + c8);
  f16x8 b1 = *(const f16x8*)(E1 + (size_t)s1 * D_ + c8);
  f16x8 a2 = *(const f16x8*)(E2 + (size_t)s0 * D_ + c8);
  f16x8 b2 = *(const f16x8*)(E2 + (size_t)s1 * D_ + c8);
  float o[8];
#pragma unroll
  for (int k = 0; k < 8; ++k)
    o[k] = w0 * ((float)a0[k] + (float)a1[k] + (float)a2[k])
         + w1 * ((float)b0[k] + (float)b1[k] + (float)b2[k]);
  *(float4*)(out + (size_t)t * D_ + c8)     = *(float4*)&o[0];
  *(float4*)(out + (size_t)t * D_ + c8 + 4) = *(float4*)&o[4];
}

extern "C" void kernel_launch(void* const* d_in, const int* in_sizes, int n_in,
                              void* d_out, int out_size, void* d_ws, size_t ws_size,
                              hipStream_t stream) {
  const float* x  = (const float*)d_in[0];
  const float* wr = (const float*)d_in[1];
  const float* w1 = (const float*)d_in[2];
  const float* b1 = (const float*)d_in[3];
  const float* w2 = (const float*)d_in[4];
  const float* b2 = (const float*)d_in[5];
  float* out = (float*)d_out;

  char* ws = (char*)d_ws;
  size_t o = 0;
  __bf16* wt  = (__bf16*)(ws + o); o += (size_t)E_ * D_ * F_ * 2;  // w1t, then w2t after GEMM1
  __bf16* Xg  = (__bf16*)(ws + o); o += (size_t)NSLOTP * D_ * 2;   // dead after GEMM1
  __bf16* H   = (__bf16*)(ws + o); o += (size_t)NSLOTP * F_ * 2;
  f16*   E1p  = (f16*)(ws + o);   o += (size_t)NSLOTP * D_ * 2;
  f16*   E2p  = (f16*)(ws + o);   o += (size_t)NSLOTP * D_ * 2;
  int*   tki  = (int*)(ws + o);   o += (size_t)NTOK * 2 * 4;
  float* tkw  = (float*)(ws + o); o += (size_t)NTOK * 2 * 4;
  int*   stok = (int*)(ws + o);   o += (size_t)NSLOTP * 4;
  int*   tslot= (int*)(ws + o);   o += (size_t)NTOK * 2 * 4;
  int*   aoff = (int*)(ws + o);   o += 64;
  f16*   E0p  = (f16*)Xg;         // alias: Xg dead after GEMM1, identical size
  if (ws_size < o) return;        // ~137 MB (< proven 147 MB)

  k_router<<<NTOK / 4, 256, 0, stream>>>(x, wr, tki, tkw);
  k_route_all<<<1, 256, 0, stream>>>(tki, stok, tslot, aoff);
  k_gather<<<(NSLOTP * D_ / 8) / 256, 256, 0, stream>>>(x, stok, Xg);
  // w1 transpose: R=768, C=3072 -> grid (48, 6, 8)
  k_transpose<<<dim3(F_ / 64, D_ / 128, E_), 256, 0, stream>>>(w1, wt, D_, F_);
  // GEMM1: 12*72 = 864 blocks (proven config)
  k_gemm1<<<(F_ / 256) * (NSLOTP / 128), 512, 0, stream>>>(Xg, wt, b1, aoff, H);
  // w2 transpose into the (now dead) wt slot: R=3072, C=768 -> grid (12, 24, 8)
  k_transpose<<<dim3(D_ / 64, F_ / 128, E_), 256, 0, stream>>>(w2, wt, F_, D_);
  // GEMM2: split-K=3 -> 3*3*72 = 648 blocks, fp16 partials
  k_gemm2<<<3 * (D_ / 256) * (NSLOTP / 128), 512, 0, stream>>>(
      H, wt, b2, aoff, E0p, E1p, E2p);
  k_combine<<<NTOK * (D_ / 8) / 256, 256, 0, stream>>>(E0p, E1p, E2p, tslot, tkw, out);
}

// Round 14
// 203.192 us; speedup vs baseline: 1.1478x; 1.0704x over previous
//
#include <hip/hip_runtime.h>
#include <math.h>

typedef __bf16 bf16x8 __attribute__((ext_vector_type(8)));
typedef float f32x4 __attribute__((ext_vector_type(4)));
typedef _Float16 f16;
typedef _Float16 f16x8 __attribute__((ext_vector_type(8)));

#define B_ 4
#define S_ 1024
#define D_ 768
#define F_ 3072
#define E_ 8
#define NTOK 4096
#define NSLOTP 9216   // 8192 slots + per-expert pad to 128

__device__ __forceinline__ void gload_lds16(const void* g, void* s) {
  __builtin_amdgcn_global_load_lds((const __attribute__((address_space(1))) void*)g,
                                   (__attribute__((address_space(3))) void*)s, 16, 0, 0);
}

__device__ __forceinline__ float gelu_f(float v) {
  float u = v * (0.7978845608f + 0.0356774081f * v * v);
  float t = 1.f - 2.f / (1.f + __expf(2.f * u));   // tanh(u), correct +/-inf limits
  return 0.5f * v * (1.f + t);
}

// ---------------- router: fp32 logits, softmax, top-2, renorm (NO atomics) ----------------
__global__ __launch_bounds__(256) void k_router(const float* __restrict__ x,
    const float* __restrict__ wr, int* __restrict__ tki, float* __restrict__ tkw) {
  int wid = threadIdx.x >> 6, lane = threadIdx.x & 63;
  int t = blockIdx.x * 4 + wid;
  const float* xp = x + (size_t)t * D_;
  float pa[E_];
#pragma unroll
  for (int e = 0; e < E_; ++e) pa[e] = 0.f;
#pragma unroll
  for (int it = 0; it < D_ / 64; ++it) {
    int d = it * 64 + lane;
    float xv = xp[d];
    const float4* wp = (const float4*)(wr + (size_t)d * E_);
    float4 a = wp[0], b = wp[1];
    pa[0] += xv * a.x; pa[1] += xv * a.y; pa[2] += xv * a.z; pa[3] += xv * a.w;
    pa[4] += xv * b.x; pa[5] += xv * b.y; pa[6] += xv * b.z; pa[7] += xv * b.w;
  }
#pragma unroll
  for (int e = 0; e < E_; ++e) {
    float v = pa[e];
    for (int off = 32; off; off >>= 1) v += __shfl_xor(v, off);
    pa[e] = v;
  }
  if (lane == 0) {
    float m = pa[0];
#pragma unroll
    for (int e = 1; e < E_; ++e) m = fmaxf(m, pa[e]);
    float p[E_], s = 0.f;
#pragma unroll
    for (int e = 0; e < E_; ++e) { p[e] = expf(pa[e] - m); s += p[e]; }
#pragma unroll
    for (int e = 0; e < E_; ++e) p[e] = p[e] / s;
    int i0 = 0; float b0 = p[0];
#pragma unroll
    for (int e = 1; e < E_; ++e) if (p[e] > b0) { b0 = p[e]; i0 = e; }
    int i1 = -1; float b1v = -1.f;
#pragma unroll
    for (int e = 0; e < E_; ++e) if (e != i0 && p[e] > b1v) { b1v = p[e]; i1 = e; }
    float den = b0 + b1v + 1e-8f;
    tki[t * 2] = i0; tki[t * 2 + 1] = i1;
    tkw[t * 2] = b0 / den; tkw[t * 2 + 1] = b1v / den;
  }
}

// ---- single-block routing: histogram -> scan -> 128-aligned offsets -> ordered slots ----
__global__ __launch_bounds__(256) void k_route_all(const int* __restrict__ tki,
    int* __restrict__ stok, int* __restrict__ tslot, int* __restrict__ aoff) {
  __shared__ int cl[256][E_ + 1];   // +1 pad: spread histogram banks
  __shared__ int tot[E_];
  __shared__ int aoffA[E_ + 1];
  int tid = threadIdx.x;
  for (int i = tid; i < NSLOTP; i += 256) stok[i] = -1;
#pragma unroll
  for (int e = 0; e < E_; ++e) cl[tid][e] = 0;
  int t0 = tid * (NTOK / 256);
#pragma unroll
  for (int i = 0; i < NTOK / 256; ++i) {
    cl[tid][tki[(t0 + i) * 2]]++;
    cl[tid][tki[(t0 + i) * 2 + 1]]++;
  }
  __syncthreads();
  if (tid < E_) {
    int run = 0;
    for (int i = 0; i < 256; ++i) { int v = cl[i][tid]; cl[i][tid] = run; run += v; }
    tot[tid] = run;
  }
  __syncthreads();
  if (tid == 0) {
    int a = 0; aoffA[0] = 0; aoff[0] = 0;
    for (int e = 0; e < E_; ++e) { a += ((tot[e] + 127) >> 7) << 7; aoffA[e + 1] = a; aoff[e + 1] = a; }
  }
  __syncthreads();
#pragma unroll
  for (int i = 0; i < NTOK / 256; ++i) {
    int t = t0 + i;
#pragma unroll
    for (int k = 0; k < 2; ++k) {
      int e = tki[t * 2 + k];
      int pos = aoffA[e] + cl[tid][e];
      cl[tid][e]++;
      stok[pos] = t;
      tslot[t * 2 + k] = pos;
    }
  }
}

// -------- gather x rows into bf16 slot matrix (zeros for padding) --------
__global__ __launch_bounds__(256) void k_gather(const float* __restrict__ x,
    const int* __restrict__ stok, __bf16* __restrict__ Xg) {
  int i8 = blockIdx.x * 256 + threadIdx.x;
  int flat = i8 * 8;
  int row = flat / D_;
  int col = flat - row * D_;
  int tok = stok[row];
  bf16x8 v;
  if (tok >= 0) {
    const float4* s = (const float4*)(x + (size_t)tok * D_ + col);
    float4 a = s[0], b = s[1];
    v[0] = (__bf16)a.x; v[1] = (__bf16)a.y; v[2] = (__bf16)a.z; v[3] = (__bf16)a.w;
    v[4] = (__bf16)b.x; v[5] = (__bf16)b.y; v[6] = (__bf16)b.z; v[7] = (__bf16)b.w;
  } else {
#pragma unroll
    for (int k = 0; k < 8; ++k) v[k] = (__bf16)0.f;
  }
  *(bf16x8*)(Xg + (size_t)flat) = v;
}

// -------- fp32 [R][C] -> bf16 [C][R] per expert; 128-row tile, 256B write segments --------
__global__ __launch_bounds__(256) void k_transpose(const float* __restrict__ in,
    __bf16* __restrict__ outp, int R, int C) {
  __shared__ float Ts[128][65];
  int e = blockIdx.z;
  int r0 = blockIdx.y * 128, c0 = blockIdx.x * 64;
  const float* ip = in + (size_t)e * R * C + (size_t)r0 * C + c0;
  int lr = threadIdx.x >> 4;          // 0..15
  int lc = (threadIdx.x & 15) * 4;    // 0..60
#pragma unroll
  for (int it = 0; it < 8; ++it) {
    int r = lr + it * 16;
    float4 v = *(const float4*)(ip + (size_t)r * C + lc);
    Ts[r][lc] = v.x; Ts[r][lc + 1] = v.y; Ts[r][lc + 2] = v.z; Ts[r][lc + 3] = v.w;
  }
  __syncthreads();
  int cc = threadIdx.x >> 4;          // 0..15 (column within pass)
  int rr = (threadIdx.x & 15) * 8;    // 0..120 (16 threads x 16B = 256B per column)
  __bf16* op = outp + (size_t)e * R * C + (size_t)c0 * R + r0 + rr;
#pragma unroll
  for (int it = 0; it < 4; ++it) {
    int c = cc + it * 16;
    bf16x8 v;
#pragma unroll
    for (int i = 0; i < 8; ++i) v[i] = (__bf16)Ts[rr + i][c];
    *(bf16x8*)(op + (size_t)c * R) = v;
  }
}

// ===== GEMM1 (proven 79.6us): 2-phase dbuf, BM=128, BN=256, BK=32, =====
// ===== 8 waves (2x4, per-wave 64x64), 48KB LDS.                     =====
// H = gelu(Xg @ w1t^T + b1)
__global__ __launch_bounds__(512, 4) void k_gemm1(
    const __bf16* __restrict__ A, const __bf16* __restrict__ Bt,
    const float* __restrict__ bias, const int* __restrict__ aoff,
    __bf16* __restrict__ Hout) {
  constexpr int KST = D_, N = F_;
  constexpr int BN = 256;
  constexpr int ASZ = 128 * 32;
  constexpr int BSZ = BN * 32;
  constexpr int NK = KST / 32;
  constexpr int NB = N / BN;
  constexpr int NMB = NSLOTP / 128;
  constexpr int NWG = NB * NMB;                    // 12*72 = 864

  __shared__ __align__(16) __bf16 Als[2 * ASZ];
  __shared__ __align__(16) __bf16 Bls[2 * BSZ];

  int bswz = (blockIdx.x & 7) * (NWG / 8) + (blockIdx.x >> 3);   // bijective, NWG%8==0
  int mb = bswz % NMB, nb = bswz / NMB;                          // mb-fast: B panel L2-hot
  int row0 = mb * 128;
  if (row0 >= aoff[E_]) return;
  int e = 0;
#pragma unroll
  for (int q = 0; q < E_; ++q) if (row0 >= aoff[q + 1]) e = q + 1;
  const __bf16* Bp = Bt + (size_t)e * D_ * F_;

  int tid = threadIdx.x, w = tid >> 6, l = tid & 63;
  int lr = l >> 2, ls = l & 3;      // staging lane -> row-in-16 / 16B slot
  int fr = l & 15, fg = l >> 4;     // fragment lane -> row / k-group
  int wrow = (w >> 2) * 64, wcol = (w & 3) * 64;

  auto STAGE = [&](int kt, int b) {
    int k0 = kt * 32;
    {
      int rowA = w * 16 + lr;
      int sA = ls ^ ((rowA >> 1) & 3);
      gload_lds16(A + (size_t)(row0 + rowA) * KST + k0 + sA * 8, Als + b * ASZ + w * 512);
    }
#pragma unroll
    for (int q = 0; q < 2; ++q) {
      int idx = w * 2 + q;
      int rowB = idx * 16 + lr;
      int sB = ls ^ ((rowB >> 1) & 3);
      gload_lds16(Bp + (size_t)(nb * BN + rowB) * KST + k0 + sB * 8, Bls + b * BSZ + idx * 512);
    }
  };

  f32x4 acc[4][4] = {};
  STAGE(0, 0);
  asm volatile("s_waitcnt vmcnt(0)" ::: "memory");
  __builtin_amdgcn_sched_barrier(0);
  __builtin_amdgcn_s_barrier();
  for (int t = 0; t < NK; ++t) {
    int cur = t & 1;
    if (t + 1 < NK) STAGE(t + 1, cur ^ 1);         // issue next-tile loads FIRST
    __builtin_amdgcn_sched_barrier(0);
    bf16x8 af[4], bfr[4];
#pragma unroll
    for (int i = 0; i < 4; ++i) {
      int rl = wrow + i * 16 + fr;
      af[i] = *(const bf16x8*)(Als + cur * ASZ + rl * 32 + ((fg ^ ((rl >> 1) & 3)) << 3));
    }
#pragma unroll
    for (int j = 0; j < 4; ++j) {
      int nl = wcol + j * 16 + fr;
      bfr[j] = *(const bf16x8*)(Bls + cur * BSZ + nl * 32 + ((fg ^ ((nl >> 1) & 3)) << 3));
    }
#pragma unroll
    for (int i = 0; i < 4; ++i)
#pragma unroll
      for (int j = 0; j < 4; ++j)
        acc[i][j] = __builtin_amdgcn_mfma_f32_16x16x32_bf16(af[i], bfr[j], acc[i][j], 0, 0, 0);
    __builtin_amdgcn_sched_barrier(0);
    asm volatile("s_waitcnt vmcnt(0)" ::: "memory");  // hidden under MFMA
    __builtin_amdgcn_s_barrier();
  }

#pragma unroll
  for (int j = 0; j < 4; ++j) {
    int col = nb * BN + wcol + j * 16 + fr;
    float bv = bias[e * N + col];
#pragma unroll
    for (int i = 0; i < 4; ++i) {
#pragma unroll
      for (int r = 0; r < 4; ++r) {
        int row = row0 + wrow + i * 16 + fg * 4 + r;
        Hout[(size_t)row * N + col] = (__bf16)gelu_f(acc[i][j][r] + bv);
      }
    }
  }
}

// ===== GEMM2 (proven): 2-phase dbuf, BM=128, BN=256, BK=32, split-K=2, fp16 partials =====
// E[kh] = H[:,khalf] @ w2t[:,khalf]^T (+b2 if kh==0).
__global__ __launch_bounds__(512, 4) void k_gemm2(
    const __bf16* __restrict__ A, const __bf16* __restrict__ Bt,
    const float* __restrict__ bias, const int* __restrict__ aoff,
    f16* __restrict__ E0, f16* __restrict__ E1) {
  constexpr int KST = F_, N = D_;
  constexpr int BN = 256;
  constexpr int ASZ = 128 * 32;
  constexpr int BSZ = BN * 32;
  constexpr int NK = KST / 32 / 2;
  constexpr int NB = N / BN;
  constexpr int NMB = NSLOTP / 128;
  constexpr int NWGB = NB * NMB;                   // 3*72 = 216
  constexpr int NWG = NWGB * 2;                    // 432

  __shared__ __align__(16) __bf16 Als[2 * ASZ];
  __shared__ __align__(16) __bf16 Bls[2 * BSZ];

  int bswz = (blockIdx.x & 7) * (NWG / 8) + (blockIdx.x >> 3);
  int kh = bswz / NWGB;
  int rem = bswz % NWGB;
  int mb = rem % NMB, nb = rem / NMB;
  int row0 = mb * 128;
  if (row0 >= aoff[E_]) return;
  int e = 0;
#pragma unroll
  for (int q = 0; q < E_; ++q) if (row0 >= aoff[q + 1]) e = q + 1;
  const __bf16* Bp = Bt + (size_t)e * D_ * F_;
  int kbase = kh * (KST / 2);

  int tid = threadIdx.x, w = tid >> 6, l = tid & 63;
  int lr = l >> 2, ls = l & 3;
  int fr = l & 15, fg = l >> 4;
  int wrow = (w >> 2) * 64, wcol = (w & 3) * 64;

  auto STAGE = [&](int kt, int b) {
    int k0 = kbase + kt * 32;
    {
      int rowA = w * 16 + lr;
      int sA = ls ^ ((rowA >> 1) & 3);
      gload_lds16(A + (size_t)(row0 + rowA) * KST + k0 + sA * 8, Als + b * ASZ + w * 512);
    }
#pragma unroll
    for (int q = 0; q < 2; ++q) {
      int idx = w * 2 + q;
      int rowB = idx * 16 + lr;
      int sB = ls ^ ((rowB >> 1) & 3);
      gload_lds16(Bp + (size_t)(nb * BN + rowB) * KST + k0 + sB * 8, Bls + b * BSZ + idx * 512);
    }
  };

  f32x4 acc[4][4] = {};
  STAGE(0, 0);
  asm volatile("s_waitcnt vmcnt(0)" ::: "memory");
  __builtin_amdgcn_sched_barrier(0);
  __builtin_amdgcn_s_barrier();
  for (int t = 0; t < NK; ++t) {
    int cur = t & 1;
    if (t + 1 < NK) STAGE(t + 1, cur ^ 1);
    __builtin_amdgcn_sched_barrier(0);
    bf16x8 af[4], bfr[4];
#pragma unroll
    for (int i = 0; i < 4; ++i) {
      int rl = wrow + i * 16 + fr;
      af[i] = *(const bf16x8*)(Als + cur * ASZ + rl * 32 + ((fg ^ ((rl >> 1) & 3)) << 3));
    }
#pragma unroll
    for (int j = 0; j < 4; ++j) {
      int nl = wcol + j * 16 + fr;
      bfr[j] = *(const bf16x8*)(Bls + cur * BSZ + nl * 32 + ((fg ^ ((nl >> 1) & 3)) << 3));
    }
#pragma unroll
    for (int i = 0; i < 4; ++i)
#pragma unroll
      for (int j = 0; j < 4; ++j)
        acc[i][j] = __builtin_amdgcn_mfma_f32_16x16x32_bf16(af[i], bfr[j], acc[i][j], 0, 0, 0);
    __builtin_amdgcn_sched_barrier(0);
    asm volatile("s_waitcnt vmcnt(0)" ::: "memory");
    __builtin_amdgcn_s_barrier();
  }

  f16* Ep = (kh == 0) ? E0 : E1;
#pragma unroll
  for (int j = 0; j < 4; ++j) {
    int col = nb * BN + wcol + j * 16 + fr;
    float bv = (kh == 0) ? bias[e * N + col] : 0.f;
#pragma unroll
    for (int i = 0; i < 4; ++i) {
#pragma unroll
      for (int r = 0; r < 4; ++r) {
        int row = row0 + wrow + i * 16 + fg * 4 + r;
        Ep[(size_t)row * N + col] = (f16)(acc[i][j][r] + bv);
      }
    }
  }
}

// -------- combine: out[t] = w0*(E0+E1)[s0] + w1*(E0+E1)[s1]  (fp16 partials) --------
__global__ __launch_bounds__(256) void k_combine(const f16* __restrict__ E0,
    const f16* __restrict__ E1, const int* __restrict__ tslot,
    const float* __restrict__ tkw, float* __restrict__ out) {
  int idx = blockIdx.x * 256 + threadIdx.x;        // per 8 elems
  int t = idx / (D_ / 8);
  int c8 = (idx - t * (D_ / 8)) * 8;
  int s0 = tslot[2 * t], s1 = tslot[2 * t + 1];
  float w0 = tkw[2 * t], w1 = tkw[2 * t + 1];
  f16x8 a0 = *(const f16x8*)(E0 + (size_t)s0 * D_ + c8);
  f16x8 b0 = *(const f16x8*)(E0 + (size_t)s1 * D_ + c8);
  f16x8 a1 = *(const f16x8*)(E1 + (size_t)s0 * D_ + c8);
  f16x8 b1 = *(const f16x8*)(E1 + (size_t)s1 * D_ + c8);
  float o[8];
#pragma unroll
  for (int k = 0; k < 8; ++k)
    o[k] = w0 * ((float)a0[k] + (float)a1[k]) + w1 * ((float)b0[k] + (float)b1[k]);
  *(float4*)(out + (size_t)t * D_ + c8)     = *(float4*)&o[0];
  *(float4*)(out + (size_t)t * D_ + c8 + 4) = *(float4*)&o[4];
}

extern "C" void kernel_launch(void* const* d_in, const int* in_sizes, int n_in,
                              void* d_out, int out_size, void* d_ws, size_t ws_size,
                              hipStream_t stream) {
  const float* x  = (const float*)d_in[0];
  const float* wr = (const float*)d_in[1];
  const float* w1 = (const float*)d_in[2];
  const float* b1 = (const float*)d_in[3];
  const float* w2 = (const float*)d_in[4];
  const float* b2 = (const float*)d_in[5];
  float* out = (float*)d_out;

  char* ws = (char*)d_ws;
  size_t o = 0;
  __bf16* wt  = (__bf16*)(ws + o); o += (size_t)E_ * D_ * F_ * 2;  // w1t, then w2t after GEMM1
  __bf16* Xg  = (__bf16*)(ws + o); o += (size_t)NSLOTP * D_ * 2;   // dead after GEMM1
  __bf16* H   = (__bf16*)(ws + o); o += (size_t)NSLOTP * F_ * 2;
  f16*   E1p  = (f16*)(ws + o);   o += (size_t)NSLOTP * D_ * 2;
  int*   tki  = (int*)(ws + o);   o += (size_t)NTOK * 2 * 4;
  float* tkw  = (float*)(ws + o); o += (size_t)NTOK * 2 * 4;
  int*   stok = (int*)(ws + o);   o += (size_t)NSLOTP * 4;
  int*   tslot= (int*)(ws + o);   o += (size_t)NTOK * 2 * 4;
  int*   aoff = (int*)(ws + o);   o += 64;
  f16*   E0p  = (f16*)Xg;         // alias: Xg dead after GEMM1, identical size
  if (ws_size < o) return;        // ~123 MB (< proven 147 MB)

  k_router<<<NTOK / 4, 256, 0, stream>>>(x, wr, tki, tkw);
  k_route_all<<<1, 256, 0, stream>>>(tki, stok, tslot, aoff);
  k_gather<<<(NSLOTP * D_ / 8) / 256, 256, 0, stream>>>(x, stok, Xg);
  // w1 transpose: R=768, C=3072 -> grid (48, 6, 8)
  k_transpose<<<dim3(F_ / 64, D_ / 128, E_), 256, 0, stream>>>(w1, wt, D_, F_);
  // GEMM1: 12*72 = 864 blocks (proven config)
  k_gemm1<<<(F_ / 256) * (NSLOTP / 128), 512, 0, stream>>>(Xg, wt, b1, aoff, H);
  // w2 transpose into the (now dead) wt slot: R=3072, C=768 -> grid (12, 24, 8)
  k_transpose<<<dim3(D_ / 64, F_ / 128, E_), 256, 0, stream>>>(w2, wt, F_, D_);
  // GEMM2: split-K=2 -> 432 blocks, fp16 partials
  k_gemm2<<<2 * (D_ / 256) * (NSLOTP / 128), 512, 0, stream>>>(
      H, wt, b2, aoff, E0p, E1p);
  k_combine<<<NTOK * (D_ / 8) / 256, 256, 0, stream>>>(E0p, E1p, tslot, tkw, out);
}